// Round 1
// baseline (709.729 us; speedup 1.0000x reference)
//
#include <hip/hip_runtime.h>
#include <math.h>

#define NND 1024

#define STEP_     (5.0f/9.0f)
#define INV_STEP_ 1.8f
#define SQ3_      1.73205080756887729f
#define INV_SQ3_  0.57735026918962576f
#define INV_NN_   0.03126527053f      /* 1/sqrt(1023) */
#define INV_S8_   0.35355339059327373f
#define INV_S32_  0.17677669529663687f

__device__ __forceinline__ float fast_rcp(float x){ return __builtin_amdgcn_rcpf(x); }
__device__ __forceinline__ float silu_f(float t){ return t * fast_rcp(1.0f + __expf(-t)); }
__device__ __forceinline__ float sigm_f(float t){ return fast_rcp(1.0f + __expf(-t)); }

// ---------------- Kernel A: node pre-GEMMs: sc = x@sc1_w/sqrt8, xl = x@lin1a_w/sqrt8
__global__ __launch_bounds__(256) void k_node_pre(
    const float* __restrict__ x, const float* __restrict__ sc1_w,
    const float* __restrict__ lin1a_w, float* __restrict__ sc, float* __restrict__ xl)
{
    int n = blockIdx.x * blockDim.x + threadIdx.x;
    if (n >= NND) return;
    float xi[8];
#pragma unroll
    for (int i = 0; i < 8; i++) xi[i] = x[n*8 + i];
#pragma unroll
    for (int k = 0; k < 32; k++){
        float a = 0.f;
#pragma unroll
        for (int i = 0; i < 8; i++) a += xi[i] * sc1_w[i*32 + k];
        sc[n*32 + k] = a * INV_S8_;
    }
#pragma unroll
    for (int k = 0; k < 8; k++){
        float a = 0.f;
#pragma unroll
        for (int i = 0; i < 8; i++) a += xi[i] * lin1a_w[i*8 + k];
        xl[n*8 + k] = a * INV_S8_;
    }
}

// ---------------- Kernel B: edge pass 1 + segment-sum into m0 (N,8), m1 (N,8,3)
// One block per dst node; each thread handles srcs tid, tid+256, ...
__global__ __launch_bounds__(256) void k_edge1(
    const float* __restrict__ pos, const float* __restrict__ xl,
    const float* __restrict__ fc1_w1, const float* __restrict__ fc1_w2,
    float* __restrict__ m0, float* __restrict__ m1)
{
    __shared__ float sW1[1000];   // (10,100)
    __shared__ float sW2[1600];   // (100,16)
    __shared__ float sred[4][32];
    const int dst = blockIdx.x;
    const int tid = threadIdx.x;
    for (int i = tid; i < 1000; i += 256) sW1[i] = fc1_w1[i];
    for (int i = tid; i < 1600; i += 256) sW2[i] = fc1_w2[i];
    __syncthreads();

    const float px = pos[dst*3+0], py = pos[dst*3+1], pz = pos[dst*3+2];
    float acc[32];
#pragma unroll
    for (int k = 0; k < 32; k++) acc[k] = 0.f;

    for (int src = tid; src < NND; src += 256){
        if (src == dst) continue;
        float vx = pos[src*3+0] - px;
        float vy = pos[src*3+1] - py;
        float vz = pos[src*3+2] - pz;
        float r  = sqrtf(vx*vx + vy*vy + vz*vz);
        float sf = SQ3_ / r;
        float y1x = vx*sf, y1y = vy*sf, y1z = vz*sf;
        float emb[10];
#pragma unroll
        for (int i = 0; i < 10; i++){
            float d = (r - (float)i * STEP_) * INV_STEP_;
            emb[i] = __expf(-d*d);           // sqrt(10) folded against /sqrt(10)
        }
        float w[16];
#pragma unroll
        for (int k = 0; k < 16; k++) w[k] = 0.f;
        for (int j = 0; j < 100; j++){
            float t = 0.f;
#pragma unroll
            for (int i = 0; i < 10; i++) t += emb[i] * sW1[i*100 + j];
            float h = silu_f(t);
#pragma unroll
            for (int k = 0; k < 16; k++) w[k] += h * sW2[j*16 + k];
        }
        const float4 x4a = *reinterpret_cast<const float4*>(&xl[src*8]);
        const float4 x4b = *reinterpret_cast<const float4*>(&xl[src*8+4]);
        float xe[8] = {x4a.x,x4a.y,x4a.z,x4a.w, x4b.x,x4b.y,x4b.z,x4b.w};
#pragma unroll
        for (int u = 0; u < 8; u++){
            float w0  = w[u]   * 0.1f;       // /sqrt(100)
            float w1v = w[8+u] * 0.1f;
            acc[u] += w0 * xe[u];
            float qv = w1v * xe[u];
            acc[8 + u*3 + 0] += qv * y1x;
            acc[8 + u*3 + 1] += qv * y1y;
            acc[8 + u*3 + 2] += qv * y1z;
        }
    }
    // block reduce (32 values over 256 threads)
#pragma unroll
    for (int off = 32; off > 0; off >>= 1){
#pragma unroll
        for (int k = 0; k < 32; k++) acc[k] += __shfl_down(acc[k], off);
    }
    const int wave = tid >> 6, lane = tid & 63;
    if (lane == 0){
#pragma unroll
        for (int k = 0; k < 32; k++) sred[wave][k] = acc[k];
    }
    __syncthreads();
    if (tid < 32){
        float v = (sred[0][tid] + sred[1][tid]) + (sred[2][tid] + sred[3][tid]);
        v *= INV_NN_;
        if (tid < 8) m0[dst*8 + tid] = v;
        else         m1[dst*24 + (tid - 8)] = v;
    }
}

// ---------------- Kernel C: node middle (everything between the two edge passes)
__global__ __launch_bounds__(128) void k_node_mid(
    const float* __restrict__ m0, const float* __restrict__ m1,
    const float* __restrict__ sc,
    const float* __restrict__ lin2a0, const float* __restrict__ lin2a1,
    const float* __restrict__ alpha1_w, const float* __restrict__ sc2_w,
    const float* __restrict__ lin1b0, const float* __restrict__ lin1b1,
    float* __restrict__ a0n, float* __restrict__ a1n, float* __restrict__ scv)
{
    int n = blockIdx.x * blockDim.x + threadIdx.x;
    if (n >= NND) return;
    float fm0[8];
#pragma unroll
    for (int u = 0; u < 8; u++) fm0[u] = m0[n*8 + u];
    float alpha = 0.f;
#pragma unroll
    for (int u = 0; u < 8; u++) alpha += fm0[u] * alpha1_w[u];
    alpha *= INV_S8_;

    float x0[16], gate[16];
#pragma unroll
    for (int k = 0; k < 32; k++){
        float o = 0.f;
#pragma unroll
        for (int u = 0; u < 8; u++) o += fm0[u] * lin2a0[u*32 + k];
        float sv = sc[n*32 + k] + alpha * (o * INV_S8_);
        if (k < 16) x0[k] = silu_f(sv);
        else        gate[k - 16] = sigm_f(sv);
    }
    float fm1[8][3];
#pragma unroll
    for (int u = 0; u < 8; u++)
#pragma unroll
        for (int c = 0; c < 3; c++) fm1[u][c] = m1[n*24 + u*3 + c];

    float x1[16][3];
#pragma unroll
    for (int v = 0; v < 16; v++){
        float o0 = 0.f, o1 = 0.f, o2 = 0.f;
#pragma unroll
        for (int u = 0; u < 8; u++){
            float wv = lin2a1[u*16 + v];
            o0 += fm1[u][0] * wv; o1 += fm1[u][1] * wv; o2 += fm1[u][2] * wv;
        }
        x1[v][0] = o0 * INV_S8_ * gate[v];
        x1[v][1] = o1 * INV_S8_ * gate[v];
        x1[v][2] = o2 * INV_S8_ * gate[v];
    }
    float s0 = 0.f, s1 = 0.f, s2 = 0.f;
#pragma unroll
    for (int u = 0; u < 16; u++){
        float wv = sc2_w[u];
        s0 += x1[u][0]*wv; s1 += x1[u][1]*wv; s2 += x1[u][2]*wv;
    }
    scv[n*3+0] = s0 * 0.25f; scv[n*3+1] = s1 * 0.25f; scv[n*3+2] = s2 * 0.25f;
#pragma unroll
    for (int v = 0; v < 16; v++){
        float a = 0.f;
#pragma unroll
        for (int u = 0; u < 16; u++) a += x0[u] * lin1b0[u*16 + v];
        a0n[n*16 + v] = a * 0.25f;
        float b0 = 0.f, b1 = 0.f, b2 = 0.f;
#pragma unroll
        for (int u = 0; u < 16; u++){
            float wv = lin1b1[u*16 + v];
            b0 += x1[u][0]*wv; b1 += x1[u][1]*wv; b2 += x1[u][2]*wv;
        }
        a1n[n*48 + v*3 + 0] = b0 * 0.25f;
        a1n[n*48 + v*3 + 1] = b1 * 0.25f;
        a1n[n*48 + v*3 + 2] = b2 * 0.25f;
    }
}

// ---------------- Kernel D: edge pass 2 + segment-sum into n0 (N,32), n1 (N,32,3)
// One block per dst; 64 edge-slots x 4 lanes. Lane q owns u-channels [4q,4q+4).
__global__ __launch_bounds__(256) void k_edge2(
    const float* __restrict__ pos,
    const float* __restrict__ a0n, const float* __restrict__ a1n,
    const float* __restrict__ fc2_w1, const float* __restrict__ fc2_w2,
    float* __restrict__ n0, float* __restrict__ n1)
{
    __shared__ float sW1[1000];   // (10,100)
    __shared__ float sW2[6400];   // (100,64)
    __shared__ float sred[4][4][32];
    const int dst = blockIdx.x;
    const int tid = threadIdx.x;
    for (int i = tid; i < 1000; i += 256) sW1[i] = fc2_w1[i];
    for (int i = tid; i < 6400; i += 256) sW2[i] = fc2_w2[i];
    __syncthreads();

    const int q = tid & 3;
    const int slot = tid >> 2;
    const int u0 = q * 4;
    const float px = pos[dst*3+0], py = pos[dst*3+1], pz = pos[dst*3+2];

    float acc[4][8];
#pragma unroll
    for (int a = 0; a < 4; a++)
#pragma unroll
        for (int b = 0; b < 8; b++) acc[a][b] = 0.f;

    for (int src = slot; src < NND; src += 64){
        if (src == dst) continue;
        float vx = pos[src*3+0] - px;
        float vy = pos[src*3+1] - py;
        float vz = pos[src*3+2] - pz;
        float r  = sqrtf(vx*vx + vy*vy + vz*vz);
        float sf = SQ3_ / r;
        float y1x = vx*sf, y1y = vy*sf, y1z = vz*sf;
        float emb[10];
#pragma unroll
        for (int i = 0; i < 10; i++){
            float d = (r - (float)i * STEP_) * INV_STEP_;
            emb[i] = __expf(-d*d);
        }
        float wa[4] = {0,0,0,0}, wb[4] = {0,0,0,0}, wc[4] = {0,0,0,0}, wd[4] = {0,0,0,0};
        for (int j = 0; j < 100; j++){
            float t = 0.f;
#pragma unroll
            for (int i = 0; i < 10; i++) t += emb[i] * sW1[i*100 + j];
            float h = silu_f(t);
            const float* w2r = &sW2[j*64 + u0];
#pragma unroll
            for (int uu = 0; uu < 4; uu++){
                wa[uu] += h * w2r[uu];
                wb[uu] += h * w2r[16 + uu];
                wc[uu] += h * w2r[32 + uu];
                wd[uu] += h * w2r[48 + uu];
            }
        }
        const float4 a0v4 = *reinterpret_cast<const float4*>(&a0n[src*16 + u0]);
        const float a0v[4] = {a0v4.x, a0v4.y, a0v4.z, a0v4.w};
        const float4 r0 = *reinterpret_cast<const float4*>(&a1n[src*48 + u0*3 + 0]);
        const float4 r1 = *reinterpret_cast<const float4*>(&a1n[src*48 + u0*3 + 4]);
        const float4 r2 = *reinterpret_cast<const float4*>(&a1n[src*48 + u0*3 + 8]);
        const float a1v[12] = {r0.x,r0.y,r0.z,r0.w, r1.x,r1.y,r1.z,r1.w, r2.x,r2.y,r2.z,r2.w};
#pragma unroll
        for (int uu = 0; uu < 4; uu++){
            float A = wa[uu]*0.1f, B = wb[uu]*0.1f, C = wc[uu]*0.1f, D = wd[uu]*0.1f;
            float a1x = a1v[uu*3+0], a1y = a1v[uu*3+1], a1z = a1v[uu*3+2];
            acc[uu][0] += A * a0v[uu];
            float dv = a1x*y1x + a1y*y1y + a1z*y1z;
            acc[uu][1] += D * dv * INV_SQ3_;
            float t2 = B * a0v[uu];
            acc[uu][2] += t2*y1x; acc[uu][3] += t2*y1y; acc[uu][4] += t2*y1z;
            acc[uu][5] += C*a1x;  acc[uu][6] += C*a1y;  acc[uu][7] += C*a1z;
        }
    }
    // reduce across the 16 slots within each wave (lanes with equal q combine)
#pragma unroll
    for (int off = 4; off <= 32; off <<= 1){
#pragma unroll
        for (int a = 0; a < 4; a++)
#pragma unroll
            for (int b = 0; b < 8; b++) acc[a][b] += __shfl_xor(acc[a][b], off);
    }
    const int wave = tid >> 6, lane = tid & 63;
    if (lane < 4){
#pragma unroll
        for (int a = 0; a < 4; a++)
#pragma unroll
            for (int b = 0; b < 8; b++) sred[wave][lane][a*8 + b] = acc[a][b];
    }
    __syncthreads();
    if (tid < 128){
        int q2 = tid >> 5;
        int k  = tid & 31;
        float v = (sred[0][q2][k] + sred[1][q2][k]) + (sred[2][q2][k] + sred[3][q2][k]);
        v *= INV_NN_;
        int uu = k >> 3, comp = k & 7;
        int u = q2*4 + uu;
        if      (comp == 0) n0[dst*32 + u] = v;
        else if (comp == 1) n0[dst*32 + 16 + u] = v;
        else if (comp < 5)  n1[dst*96 + u*3 + (comp - 2)] = v;
        else                n1[dst*96 + (16 + u)*3 + (comp - 5)] = v;
    }
}

// ---------------- Kernel E: final per-node combine + global reduction -> out[3]
__global__ __launch_bounds__(256) void k_final(
    const float* __restrict__ n0, const float* __restrict__ n1,
    const float* __restrict__ scv, const float* __restrict__ lin2b,
    const float* __restrict__ alpha2_w, float* __restrict__ out)
{
    __shared__ float sred[4][3];
    const int tid = threadIdx.x;
    float acc0 = 0.f, acc1 = 0.f, acc2 = 0.f;
    for (int n = tid; n < NND; n += 256){
        float ov0 = 0.f, ov1 = 0.f, ov2 = 0.f, al = 0.f;
#pragma unroll
        for (int u = 0; u < 32; u++){
            float w = lin2b[u];
            ov0 += n1[n*96 + u*3 + 0] * w;
            ov1 += n1[n*96 + u*3 + 1] * w;
            ov2 += n1[n*96 + u*3 + 2] * w;
            al  += n0[n*32 + u] * alpha2_w[u];
        }
        al *= INV_S32_;
        acc0 += scv[n*3+0] + al * ov0 * INV_S32_;
        acc1 += scv[n*3+1] + al * ov1 * INV_S32_;
        acc2 += scv[n*3+2] + al * ov2 * INV_S32_;
    }
#pragma unroll
    for (int off = 32; off > 0; off >>= 1){
        acc0 += __shfl_down(acc0, off);
        acc1 += __shfl_down(acc1, off);
        acc2 += __shfl_down(acc2, off);
    }
    const int wave = tid >> 6, lane = tid & 63;
    if (lane == 0){ sred[wave][0] = acc0; sred[wave][1] = acc1; sred[wave][2] = acc2; }
    __syncthreads();
    if (tid == 0){
        float o0 = sred[0][0] + sred[1][0] + sred[2][0] + sred[3][0];
        float o1 = sred[0][1] + sred[1][1] + sred[2][1] + sred[3][1];
        float o2 = sred[0][2] + sred[1][2] + sred[2][2] + sred[3][2];
        out[0] = o0 * (1.0f/32.0f);   // 1/sqrt(1024)
        out[1] = o1 * (1.0f/32.0f);
        out[2] = o2 * (1.0f/32.0f);
    }
}

extern "C" void kernel_launch(void* const* d_in, const int* in_sizes, int n_in,
                              void* d_out, int out_size, void* d_ws, size_t ws_size,
                              hipStream_t stream)
{
    const float* pos      = (const float*)d_in[0];
    const float* x        = (const float*)d_in[1];
    // d_in[2], d_in[3]: edge_src/edge_dst — dense all-pairs graph, enumerated directly
    const float* sc1_w    = (const float*)d_in[4];
    const float* lin1a_w  = (const float*)d_in[5];
    const float* fc1_w1   = (const float*)d_in[6];
    const float* fc1_w2   = (const float*)d_in[7];
    const float* lin2a0   = (const float*)d_in[8];
    const float* lin2a1   = (const float*)d_in[9];
    const float* alpha1_w = (const float*)d_in[10];
    const float* sc2_w    = (const float*)d_in[11];
    const float* lin1b0   = (const float*)d_in[12];
    const float* lin1b1   = (const float*)d_in[13];
    const float* fc2_w1   = (const float*)d_in[14];
    const float* fc2_w2   = (const float*)d_in[15];
    const float* lin2b    = (const float*)d_in[16];
    const float* alpha2_w = (const float*)d_in[17];

    float* ws  = (float*)d_ws;
    float* sc  = ws;             // 1024*32
    float* xl  = sc  + 32768;    // 1024*8
    float* m0  = xl  + 8192;     // 1024*8
    float* m1  = m0  + 8192;     // 1024*24
    float* a0n = m1  + 24576;    // 1024*16
    float* a1n = a0n + 16384;    // 1024*48
    float* scv = a1n + 49152;    // 1024*3
    float* n0  = scv + 3072;     // 1024*32
    float* n1  = n0  + 32768;    // 1024*96

    k_node_pre<<<4, 256, 0, stream>>>(x, sc1_w, lin1a_w, sc, xl);
    k_edge1<<<NND, 256, 0, stream>>>(pos, xl, fc1_w1, fc1_w2, m0, m1);
    k_node_mid<<<8, 128, 0, stream>>>(m0, m1, sc, lin2a0, lin2a1, alpha1_w, sc2_w,
                                      lin1b0, lin1b1, a0n, a1n, scv);
    k_edge2<<<NND, 256, 0, stream>>>(pos, a0n, a1n, fc2_w1, fc2_w2, n0, n1);
    k_final<<<1, 256, 0, stream>>>(n0, n1, scv, lin2b, alpha2_w, (float*)d_out);
}

// Round 3
// 183.694 us; speedup vs baseline: 3.8636x; 3.8636x over previous
//
#include <hip/hip_runtime.h>
#include <hip/hip_bf16.h>
#include <math.h>

#define NND 1024

#define STEP_     (5.0f/9.0f)
#define INV_STEP_ 1.8f
#define SQ3_      1.73205080756887729f
#define INV_SQ3_  0.57735026918962576f
#define INV_NN_   0.03126527053f      /* 1/sqrt(1023) */
#define INV_S8_   0.35355339059327373f
#define INV_S32_  0.17677669529663687f

typedef float f32x4 __attribute__((ext_vector_type(4)));
typedef short short8 __attribute__((ext_vector_type(8)));

__device__ __forceinline__ float fast_rcp(float x){ return __builtin_amdgcn_rcpf(x); }
__device__ __forceinline__ float silu_f(float t){ return t * fast_rcp(1.0f + __expf(-t)); }
__device__ __forceinline__ float sigm_f(float t){ return fast_rcp(1.0f + __expf(-t)); }

// f32 -> bf16 bits (round-to-nearest-even)
__device__ __forceinline__ short f2b(float x){
    union { float f; unsigned u; } v; v.f = x;
    unsigned r = (v.u + 0x7FFFu + ((v.u >> 16) & 1u)) >> 16;
    return (short)(r & 0xFFFFu);
}

// B-fragment for mfma_f32_16x16x32_bf16: col = lane&15, k = kbase + e
template<int KREAL, int NCOLS>
__device__ __forceinline__ short8 load_bfrag(const float* __restrict__ W, int kbase, int ncol){
    short8 f;
#pragma unroll
    for (int e = 0; e < 8; e++){
        int k = kbase + e;
        float v = (k < KREAL && ncol < NCOLS) ? W[k*NCOLS + ncol] : 0.f;
        f[e] = f2b(v);
    }
    return f;
}

// ---------------- Kernel A: node pre-GEMMs
__global__ __launch_bounds__(256) void k_node_pre(
    const float* __restrict__ x, const float* __restrict__ sc1_w,
    const float* __restrict__ lin1a_w, float* __restrict__ sc, float* __restrict__ xl)
{
    int n = blockIdx.x * blockDim.x + threadIdx.x;
    if (n >= NND) return;
    float xi[8];
#pragma unroll
    for (int i = 0; i < 8; i++) xi[i] = x[n*8 + i];
#pragma unroll
    for (int k = 0; k < 32; k++){
        float a = 0.f;
#pragma unroll
        for (int i = 0; i < 8; i++) a += xi[i] * sc1_w[i*32 + k];
        sc[n*32 + k] = a * INV_S8_;
    }
#pragma unroll
    for (int k = 0; k < 8; k++){
        float a = 0.f;
#pragma unroll
        for (int i = 0; i < 8; i++) a += xi[i] * lin1a_w[i*8 + k];
        xl[n*8 + k] = a * INV_S8_;
    }
}

// ---------------- Kernel B: edge pass 1 via MFMA
__global__ __launch_bounds__(256,3) void k_edge1_mfma(
    const float* __restrict__ pos, const float* __restrict__ xl,
    const float* __restrict__ fc1_w1, const float* __restrict__ fc1_w2,
    float* __restrict__ m0, float* __restrict__ m1)
{
    __shared__ __align__(16) short hlds[4][2176];   // per-wave 16 x 136 bf16, row stride 272B
    __shared__ float y1s[4][16][4];
    __shared__ float sred[4][32];

    const int tid  = threadIdx.x;
    const int wv   = tid >> 6;
    const int lane = tid & 63;
    const int col  = lane & 15;
    const int grp  = lane >> 4;
    const int dst  = blockIdx.x;

    // FULL zero-init: 4 waves * 2176 shorts = 4352 ints (round-2 bug: only 2176 cleared
    // -> waves 2/3 read garbage bf16 (Inf/NaN) in padded K range; Inf*0 = NaN in MFMA)
    for (int i = tid; i < 4352; i += 256) ((int*)hlds)[i] = 0;

    short8 w1f[7];
#pragma unroll
    for (int t = 0; t < 7; t++) w1f[t] = load_bfrag<10,100>(fc1_w1, grp*8, t*16 + col);
    short8 w2f[4];
#pragma unroll
    for (int s = 0; s < 4; s++) w2f[s] = load_bfrag<100,16>(fc1_w2, s*32 + grp*8, col);

    const float qx = pos[dst*3+0], qy = pos[dst*3+1], qz = pos[dst*3+2];
    float acc0 = 0.f, acc1 = 0.f, acc2 = 0.f, acc3 = 0.f;

    __syncthreads();

    char* hbase = (char*)&hlds[wv][0];
    const int rb = col*272;
    const int rmask = (col & 7) << 4;

    for (int tile = 0; tile < 16; ++tile){
        const int sbase = wv*256 + tile*16;
        {
            int s = sbase + col;
            float dx = pos[s*3+0]-qx, dy = pos[s*3+1]-qy, dz = pos[s*3+2]-qz;
            float r2 = dx*dx + dy*dy + dz*dz;
            bool valid = (s != dst);
            float rinv = valid ? __builtin_amdgcn_rsqf(r2) : 0.f;
            float r  = r2 * rinv;
            float sf = SQ3_ * rinv;
            if (grp == 0){
                y1s[wv][col][0] = dx*sf;
                y1s[wv][col][1] = dy*sf;
                y1s[wv][col][2] = dz*sf;
            }
            short8 af1;
#pragma unroll
            for (int e = 0; e < 8; e++){
                int k = grp*8 + e;
                float v = 0.f;
                if (k < 10){
                    float d = (r - (float)k*STEP_) * INV_STEP_;
                    v = __expf(-d*d);      // sqrt(10) folded against /sqrt(10)
                }
                af1[e] = valid ? f2b(v) : (short)0;
            }
            f32x4 zero4 = {0.f, 0.f, 0.f, 0.f};
#pragma unroll
            for (int t = 0; t < 7; t++){
                f32x4 c1 = __builtin_amdgcn_mfma_f32_16x16x32_bf16(af1, w1f[t], zero4, 0, 0, 0);
#pragma unroll
                for (int rg = 0; rg < 4; rg++){
                    int r_ = grp*4 + rg;
                    float h = silu_f(c1[rg]);
                    int off = r_*272 + (((t*32 + col*2)) ^ ((r_ & 7) << 4));
                    *(short*)(hbase + off) = f2b(h);
                }
            }
        }
        // --- GEMM2: h @ W2 (100x16), 4 K-steps
        f32x4 c2 = {0.f, 0.f, 0.f, 0.f};
#pragma unroll
        for (int s = 0; s < 4; s++){
            int off = rb + ((s*64 + grp*16) ^ rmask);
            short8 a2 = *(const short8*)(hbase + off);
            c2 = __builtin_amdgcn_mfma_f32_16x16x32_bf16(a2, w2f[s], c2, 0, 0, 0);
        }
        // --- epilogue in C layout: u = col, rows = grp*4+rg
#pragma unroll
        for (int rg = 0; rg < 4; rg++){
            int row = grp*4 + rg;
            int s = sbase + row;
            float y1x = y1s[wv][row][0], y1y = y1s[wv][row][1], y1z = y1s[wv][row][2];
            float xe = xl[s*8 + (col & 7)];
            float pv = c2[rg] * xe;           // 0.1 scale folded at the end
            if (col < 8){
                acc0 += pv;
            } else {
                acc1 += pv*y1x; acc2 += pv*y1y; acc3 += pv*y1z;
            }
        }
    }
    acc0 += __shfl_xor(acc0, 16); acc0 += __shfl_xor(acc0, 32);
    acc1 += __shfl_xor(acc1, 16); acc1 += __shfl_xor(acc1, 32);
    acc2 += __shfl_xor(acc2, 16); acc2 += __shfl_xor(acc2, 32);
    acc3 += __shfl_xor(acc3, 16); acc3 += __shfl_xor(acc3, 32);
    if (lane < 8){
        sred[wv][lane] = acc0;
    } else if (lane < 16){
        int uu = lane - 8;
        sred[wv][8 + uu*3 + 0] = acc1;
        sred[wv][8 + uu*3 + 1] = acc2;
        sred[wv][8 + uu*3 + 2] = acc3;
    }
    __syncthreads();
    if (tid < 32){
        float v = (sred[0][tid] + sred[1][tid]) + (sred[2][tid] + sred[3][tid]);
        v *= INV_NN_ * 0.1f;
        if (tid < 8) m0[dst*8 + tid] = v;
        else         m1[dst*24 + (tid - 8)] = v;
    }
}

// ---------------- Kernel C: node middle
__global__ __launch_bounds__(128) void k_node_mid(
    const float* __restrict__ m0, const float* __restrict__ m1,
    const float* __restrict__ sc,
    const float* __restrict__ lin2a0, const float* __restrict__ lin2a1,
    const float* __restrict__ alpha1_w, const float* __restrict__ sc2_w,
    const float* __restrict__ lin1b0, const float* __restrict__ lin1b1,
    float* __restrict__ a0n, float* __restrict__ a1n, float* __restrict__ scv)
{
    int n = blockIdx.x * blockDim.x + threadIdx.x;
    if (n >= NND) return;
    float fm0[8];
#pragma unroll
    for (int u = 0; u < 8; u++) fm0[u] = m0[n*8 + u];
    float alpha = 0.f;
#pragma unroll
    for (int u = 0; u < 8; u++) alpha += fm0[u] * alpha1_w[u];
    alpha *= INV_S8_;

    float x0[16], gate[16];
#pragma unroll
    for (int k = 0; k < 32; k++){
        float o = 0.f;
#pragma unroll
        for (int u = 0; u < 8; u++) o += fm0[u] * lin2a0[u*32 + k];
        float sv = sc[n*32 + k] + alpha * (o * INV_S8_);
        if (k < 16) x0[k] = silu_f(sv);
        else        gate[k - 16] = sigm_f(sv);
    }
    float fm1[8][3];
#pragma unroll
    for (int u = 0; u < 8; u++)
#pragma unroll
        for (int c = 0; c < 3; c++) fm1[u][c] = m1[n*24 + u*3 + c];

    float x1[16][3];
#pragma unroll
    for (int v = 0; v < 16; v++){
        float o0 = 0.f, o1 = 0.f, o2 = 0.f;
#pragma unroll
        for (int u = 0; u < 8; u++){
            float wv = lin2a1[u*16 + v];
            o0 += fm1[u][0] * wv; o1 += fm1[u][1] * wv; o2 += fm1[u][2] * wv;
        }
        x1[v][0] = o0 * INV_S8_ * gate[v];
        x1[v][1] = o1 * INV_S8_ * gate[v];
        x1[v][2] = o2 * INV_S8_ * gate[v];
    }
    float s0 = 0.f, s1 = 0.f, s2 = 0.f;
#pragma unroll
    for (int u = 0; u < 16; u++){
        float wv = sc2_w[u];
        s0 += x1[u][0]*wv; s1 += x1[u][1]*wv; s2 += x1[u][2]*wv;
    }
    scv[n*3+0] = s0 * 0.25f; scv[n*3+1] = s1 * 0.25f; scv[n*3+2] = s2 * 0.25f;
#pragma unroll
    for (int v = 0; v < 16; v++){
        float a = 0.f;
#pragma unroll
        for (int u = 0; u < 16; u++) a += x0[u] * lin1b0[u*16 + v];
        a0n[n*16 + v] = a * 0.25f;
        float b0 = 0.f, b1 = 0.f, b2 = 0.f;
#pragma unroll
        for (int u = 0; u < 16; u++){
            float wv = lin1b1[u*16 + v];
            b0 += x1[u][0]*wv; b1 += x1[u][1]*wv; b2 += x1[u][2]*wv;
        }
        a1n[n*48 + v*3 + 0] = b0 * 0.25f;
        a1n[n*48 + v*3 + 1] = b1 * 0.25f;
        a1n[n*48 + v*3 + 2] = b2 * 0.25f;
    }
}

// ---------------- Kernel D: edge pass 2 via MFMA
__global__ __launch_bounds__(256,2) void k_edge2_mfma(
    const float* __restrict__ pos,
    const float* __restrict__ a0n, const float* __restrict__ a1n,
    const float* __restrict__ fc2_w1, const float* __restrict__ fc2_w2,
    float* __restrict__ n0, float* __restrict__ n1)
{
    __shared__ __align__(16) short hlds[4][2176];
    __shared__ float y1s[4][16][4];
    __shared__ float sred[4][16][8];

    const int tid  = threadIdx.x;
    const int wv   = tid >> 6;
    const int lane = tid & 63;
    const int col  = lane & 15;
    const int grp  = lane >> 4;
    const int dst  = blockIdx.x;

    // FULL zero-init (see k_edge1 comment)
    for (int i = tid; i < 4352; i += 256) ((int*)hlds)[i] = 0;

    short8 w1f[7];
#pragma unroll
    for (int t = 0; t < 7; t++) w1f[t] = load_bfrag<10,100>(fc2_w1, grp*8, t*16 + col);
    short8 w2f[4][4];   // [kstep][ntile], ntile q covers cols q*16..q*16+15 = wa/wb/wc/wd
#pragma unroll
    for (int s = 0; s < 4; s++)
#pragma unroll
        for (int q = 0; q < 4; q++)
            w2f[s][q] = load_bfrag<100,64>(fc2_w2, s*32 + grp*8, q*16 + col);

    const float qx = pos[dst*3+0], qy = pos[dst*3+1], qz = pos[dst*3+2];
    float acc[8];
#pragma unroll
    for (int b = 0; b < 8; b++) acc[b] = 0.f;

    __syncthreads();

    char* hbase = (char*)&hlds[wv][0];
    const int rb = col*272;
    const int rmask = (col & 7) << 4;

    for (int tile = 0; tile < 16; ++tile){
        const int sbase = wv*256 + tile*16;
        {
            int s = sbase + col;
            float dx = pos[s*3+0]-qx, dy = pos[s*3+1]-qy, dz = pos[s*3+2]-qz;
            float r2 = dx*dx + dy*dy + dz*dz;
            bool valid = (s != dst);
            float rinv = valid ? __builtin_amdgcn_rsqf(r2) : 0.f;
            float r  = r2 * rinv;
            float sf = SQ3_ * rinv;
            if (grp == 0){
                y1s[wv][col][0] = dx*sf;
                y1s[wv][col][1] = dy*sf;
                y1s[wv][col][2] = dz*sf;
            }
            short8 af1;
#pragma unroll
            for (int e = 0; e < 8; e++){
                int k = grp*8 + e;
                float v = 0.f;
                if (k < 10){
                    float d = (r - (float)k*STEP_) * INV_STEP_;
                    v = __expf(-d*d);
                }
                af1[e] = valid ? f2b(v) : (short)0;
            }
            f32x4 zero4 = {0.f, 0.f, 0.f, 0.f};
#pragma unroll
            for (int t = 0; t < 7; t++){
                f32x4 c1 = __builtin_amdgcn_mfma_f32_16x16x32_bf16(af1, w1f[t], zero4, 0, 0, 0);
#pragma unroll
                for (int rg = 0; rg < 4; rg++){
                    int r_ = grp*4 + rg;
                    float h = silu_f(c1[rg]);
                    int off = r_*272 + (((t*32 + col*2)) ^ ((r_ & 7) << 4));
                    *(short*)(hbase + off) = f2b(h);
                }
            }
        }
        f32x4 c2[4];
#pragma unroll
        for (int q = 0; q < 4; q++) c2[q] = (f32x4){0.f, 0.f, 0.f, 0.f};
#pragma unroll
        for (int s = 0; s < 4; s++){
            int off = rb + ((s*64 + grp*16) ^ rmask);
            short8 a2 = *(const short8*)(hbase + off);
#pragma unroll
            for (int q = 0; q < 4; q++)
                c2[q] = __builtin_amdgcn_mfma_f32_16x16x32_bf16(a2, w2f[s][q], c2[q], 0, 0, 0);
        }
        // epilogue: u = col; wa=c2[0], wb=c2[1], wc=c2[2], wd=c2[3] (0.1 folded at end)
#pragma unroll
        for (int rg = 0; rg < 4; rg++){
            int row = grp*4 + rg;
            int s = sbase + row;
            float y1x = y1s[wv][row][0], y1y = y1s[wv][row][1], y1z = y1s[wv][row][2];
            float a0v = a0n[s*16 + col];
            float a1x = a1n[s*48 + col*3 + 0];
            float a1y = a1n[s*48 + col*3 + 1];
            float a1z = a1n[s*48 + col*3 + 2];
            float A = c2[0][rg], B = c2[1][rg], C = c2[2][rg], D = c2[3][rg];
            acc[0] += A*a0v;
            float dv = a1x*y1x + a1y*y1y + a1z*y1z;
            acc[1] += D*dv;
            float t2 = B*a0v;
            acc[2] += t2*y1x; acc[3] += t2*y1y; acc[4] += t2*y1z;
            acc[5] += C*a1x;  acc[6] += C*a1y;  acc[7] += C*a1z;
        }
    }
#pragma unroll
    for (int b = 0; b < 8; b++){
        acc[b] += __shfl_xor(acc[b], 16);
        acc[b] += __shfl_xor(acc[b], 32);
    }
    if (lane < 16){
#pragma unroll
        for (int b = 0; b < 8; b++) sred[wv][lane][b] = acc[b];
    }
    __syncthreads();
    if (tid < 128){
        int u = tid >> 3, cp = tid & 7;
        float v = sred[0][u][cp] + sred[1][u][cp] + sred[2][u][cp] + sred[3][u][cp];
        v *= INV_NN_ * 0.1f;
        if      (cp == 0) n0[dst*32 + u] = v;
        else if (cp == 1) n0[dst*32 + 16 + u] = v * INV_SQ3_;
        else if (cp < 5)  n1[dst*96 + u*3 + (cp-2)] = v;
        else              n1[dst*96 + (16+u)*3 + (cp-5)] = v;
    }
}

// ---------------- Kernel E: final combine + reduction
__global__ __launch_bounds__(256) void k_final(
    const float* __restrict__ n0, const float* __restrict__ n1,
    const float* __restrict__ scv, const float* __restrict__ lin2b,
    const float* __restrict__ alpha2_w, float* __restrict__ out)
{
    __shared__ float sred[4][3];
    const int tid = threadIdx.x;
    float acc0 = 0.f, acc1 = 0.f, acc2 = 0.f;
    for (int n = tid; n < NND; n += 256){
        float ov0 = 0.f, ov1 = 0.f, ov2 = 0.f, al = 0.f;
#pragma unroll
        for (int u = 0; u < 32; u++){
            float w = lin2b[u];
            ov0 += n1[n*96 + u*3 + 0] * w;
            ov1 += n1[n*96 + u*3 + 1] * w;
            ov2 += n1[n*96 + u*3 + 2] * w;
            al  += n0[n*32 + u] * alpha2_w[u];
        }
        al *= INV_S32_;
        acc0 += scv[n*3+0] + al * ov0 * INV_S32_;
        acc1 += scv[n*3+1] + al * ov1 * INV_S32_;
        acc2 += scv[n*3+2] + al * ov2 * INV_S32_;
    }
#pragma unroll
    for (int off = 32; off > 0; off >>= 1){
        acc0 += __shfl_down(acc0, off);
        acc1 += __shfl_down(acc1, off);
        acc2 += __shfl_down(acc2, off);
    }
    const int wave = tid >> 6, lane = tid & 63;
    if (lane == 0){ sred[wave][0] = acc0; sred[wave][1] = acc1; sred[wave][2] = acc2; }
    __syncthreads();
    if (tid == 0){
        out[0] = (sred[0][0] + sred[1][0] + sred[2][0] + sred[3][0]) * (1.0f/32.0f);
        out[1] = (sred[0][1] + sred[1][1] + sred[2][1] + sred[3][1]) * (1.0f/32.0f);
        out[2] = (sred[0][2] + sred[1][2] + sred[2][2] + sred[3][2]) * (1.0f/32.0f);
    }
}

extern "C" void kernel_launch(void* const* d_in, const int* in_sizes, int n_in,
                              void* d_out, int out_size, void* d_ws, size_t ws_size,
                              hipStream_t stream)
{
    const float* pos      = (const float*)d_in[0];
    const float* x        = (const float*)d_in[1];
    // d_in[2], d_in[3]: edge_src/edge_dst — dense all-pairs graph, enumerated directly
    const float* sc1_w    = (const float*)d_in[4];
    const float* lin1a_w  = (const float*)d_in[5];
    const float* fc1_w1   = (const float*)d_in[6];
    const float* fc1_w2   = (const float*)d_in[7];
    const float* lin2a0   = (const float*)d_in[8];
    const float* lin2a1   = (const float*)d_in[9];
    const float* alpha1_w = (const float*)d_in[10];
    const float* sc2_w    = (const float*)d_in[11];
    const float* lin1b0   = (const float*)d_in[12];
    const float* lin1b1   = (const float*)d_in[13];
    const float* fc2_w1   = (const float*)d_in[14];
    const float* fc2_w2   = (const float*)d_in[15];
    const float* lin2b    = (const float*)d_in[16];
    const float* alpha2_w = (const float*)d_in[17];

    float* ws  = (float*)d_ws;
    float* sc  = ws;             // 1024*32
    float* xl  = sc  + 32768;    // 1024*8
    float* m0  = xl  + 8192;     // 1024*8
    float* m1  = m0  + 8192;     // 1024*24
    float* a0n = m1  + 24576;    // 1024*16
    float* a1n = a0n + 16384;    // 1024*48
    float* scv = a1n + 49152;    // 1024*3
    float* n0  = scv + 3072;     // 1024*32
    float* n1  = n0  + 32768;    // 1024*96

    k_node_pre<<<4, 256, 0, stream>>>(x, sc1_w, lin1a_w, sc, xl);
    k_edge1_mfma<<<NND, 256, 0, stream>>>(pos, xl, fc1_w1, fc1_w2, m0, m1);
    k_node_mid<<<8, 128, 0, stream>>>(m0, m1, sc, lin2a0, lin2a1, alpha1_w, sc2_w,
                                      lin1b0, lin1b1, a0n, a1n, scv);
    k_edge2_mfma<<<NND, 256, 0, stream>>>(pos, a0n, a1n, fc2_w1, fc2_w2, n0, n1);
    k_final<<<1, 256, 0, stream>>>(n0, n1, scv, lin2b, alpha2_w, (float*)d_out);
}